// Round 1
// baseline (92.717 us; speedup 1.0000x reference)
//
#include <hip/hip_runtime.h>
#include <math.h>

// C = A(MxK) @ B(KxN) + bias(N), row-major, all f32.
// 64x64 tile, 256 threads, 4x4 per thread, BK=16.
__global__ __launch_bounds__(256) void gemm_bias_kernel(
    const float* __restrict__ A, const float* __restrict__ B,
    const float* __restrict__ bias, float* __restrict__ C,
    int M, int N, int K)
{
    __shared__ float As[16][68];   // As[k][m], padded stride 68 (16B-aligned rows)
    __shared__ float Bs[16][68];   // Bs[k][n]
    const int tid = threadIdx.x;
    const int tx = tid & 15, ty = tid >> 4;          // tx: n-dir, ty: m-dir
    const int row0 = blockIdx.y * 64, col0 = blockIdx.x * 64;
    const int lm = tid >> 2, lk = (tid & 3) * 4;     // A-tile load coords
    const int lbk = tid >> 4, lbn = (tid & 15) * 4;  // B-tile load coords

    float acc[4][4] = {};

    for (int k0 = 0; k0 < K; k0 += 16) {
        float4 a = *(const float4*)&A[(size_t)(row0 + lm) * K + k0 + lk];
        As[lk + 0][lm] = a.x;
        As[lk + 1][lm] = a.y;
        As[lk + 2][lm] = a.z;
        As[lk + 3][lm] = a.w;
        float4 b = *(const float4*)&B[(size_t)(k0 + lbk) * N + col0 + lbn];
        *(float4*)&Bs[lbk][lbn] = b;
        __syncthreads();
        #pragma unroll
        for (int k = 0; k < 16; ++k) {
            float4 av = *(float4*)&As[k][ty * 4];
            float4 bv = *(float4*)&Bs[k][tx * 4];
            float ar[4] = {av.x, av.y, av.z, av.w};
            float br[4] = {bv.x, bv.y, bv.z, bv.w};
            #pragma unroll
            for (int i = 0; i < 4; ++i)
                #pragma unroll
                for (int jj = 0; jj < 4; ++jj)
                    acc[i][jj] += ar[i] * br[jj];
        }
        __syncthreads();
    }

    float4 bv = *(const float4*)&bias[col0 + tx * 4];
    #pragma unroll
    for (int i = 0; i < 4; ++i) {
        float4 o;
        o.x = acc[i][0] + bv.x;
        o.y = acc[i][1] + bv.y;
        o.z = acc[i][2] + bv.z;
        o.w = acc[i][3] + bv.w;
        *(float4*)&C[(size_t)(row0 + ty * 4 + i) * N + col0 + tx * 4] = o;
    }
}

// One block per (bt, i): blk = bt*32 + i.  256 threads.
// qkv: (4096, 768) rows = [q(256) | k(256) | v(256)]
// bias: (4096, 32, 256) -> per block a contiguous 8192-float slab
// mask: (4096,) int32 (bool from JAX), indexed [bt*32 + j]
// attn_out: (4096, 256)
__global__ __launch_bounds__(256) void relattn_kernel(
    const float* __restrict__ qkv, const float* __restrict__ bias,
    const int* __restrict__ mask, float* __restrict__ attn_out)
{
    __shared__ float bias_lds[8192];  // swizzled float4 layout: (j, c) stored at c^(j&7)
    __shared__ float p_lds[256];      // p_lds[h*32 + j]

    const int blk = blockIdx.x;       // bt*32 + i
    const int bt = blk >> 5;
    const int tid = threadIdx.x;

    // ---- stage bias slab (32 KB) into LDS, XOR-swizzled at float4 granularity ----
    const float* bsrc = bias + (size_t)blk * 8192;
    #pragma unroll
    for (int it = 0; it < 8; ++it) {
        int idx4 = it * 256 + tid;              // 0..2047 linear float4 index
        float4 v = *(const float4*)(bsrc + (size_t)idx4 * 4);
        int j = idx4 >> 6, c = idx4 & 63;
        int dst4 = (j << 6) | (c ^ (j & 7));
        *(float4*)&bias_lds[dst4 * 4] = v;
    }
    __syncthreads();

    // ---- scores: thread = (h, j); s[h][j] = q[h,:] . (k[j,h,:] + bias[j,h,:]) ----
    const int j = tid & 31, h = tid >> 5;
    const float* qrow = qkv + (size_t)blk * 768 + h * 32;
    const float* krow = qkv + (size_t)(bt * 32 + j) * 768 + 256 + h * 32;
    float s = 0.f;
    #pragma unroll
    for (int d4 = 0; d4 < 8; ++d4) {
        float4 qv = *(const float4*)(qrow + d4 * 4);
        float4 kv = *(const float4*)(krow + d4 * 4);
        int c = (h * 8 + d4) ^ (j & 7);
        float4 bv = *(const float4*)&bias_lds[(j * 64 + c) * 4];
        s += qv.x * (kv.x + bv.x) + qv.y * (kv.y + bv.y)
           + qv.z * (kv.z + bv.z) + qv.w * (kv.w + bv.w);
    }
    s *= 0.17677669529663687f;  // 1/sqrt(32)

    const bool alive = (mask[bt * 32 + j] != 0);
    s = alive ? s : -__builtin_inff();

    float m = s;
    #pragma unroll
    for (int off = 16; off; off >>= 1) m = fmaxf(m, __shfl_xor(m, off));
    const bool dead = (m == -__builtin_inff());
    float p = alive ? __expf(s - m) : 0.f;     // dead row -> all lanes 0
    float l = p;
    #pragma unroll
    for (int off = 16; off; off >>= 1) l += __shfl_xor(l, off);
    float pn = dead ? 0.f : p / l;
    p_lds[tid] = pn;                            // == p_lds[h*32 + j]
    __syncthreads();

    // ---- PV: thread = (h2, d), h2*32+d == tid; o = sum_j p[h2,j]*(v[j,h2,d]+bias[j,h2,d]) ----
    const float* vcol = qkv + (size_t)bt * 32 * 768 + 512 + tid;  // + j*768 per step
    const int hbase = tid & 0xE0;               // h2*32
    float o = 0.f;
    #pragma unroll
    for (int jj = 0; jj < 32; ++jj) {
        float pv = p_lds[hbase + jj];
        float vv = vcol[(size_t)jj * 768];
        int cblk = (tid >> 2) ^ (jj & 7);       // (h2*8 + d/4) ^ (jj&7)
        float bb = bias_lds[(jj * 64 + cblk) * 4 + (tid & 3)];
        o += pv * (vv + bb);
    }
    attn_out[(size_t)blk * 256 + tid] = o;
}

extern "C" void kernel_launch(void* const* d_in, const int* in_sizes, int n_in,
                              void* d_out, int out_size, void* d_ws, size_t ws_size,
                              hipStream_t stream) {
    const float* x      = (const float*)d_in[0];   // (128,32,256)
    const float* bias_f = (const float*)d_in[1];   // (128,32,32,256)
    const int*   mask   = (const int*)d_in[2];     // (4096,)
    const float* w_qkv  = (const float*)d_in[3];   // (256,768)
    const float* b_qkv  = (const float*)d_in[4];   // (768,)
    const float* w_proj = (const float*)d_in[5];   // (256,256)
    const float* b_proj = (const float*)d_in[6];   // (256,)
    float* out = (float*)d_out;                    // (128,32,256)

    float* qkv      = (float*)d_ws;                       // 4096*768 f32
    float* attn_out = qkv + (size_t)4096 * 768;           // 4096*256 f32

    // qkv = x @ w_qkv + b_qkv
    gemm_bias_kernel<<<dim3(768 / 64, 4096 / 64), 256, 0, stream>>>(
        x, w_qkv, b_qkv, qkv, 4096, 768, 256);

    // fused relational attention
    relattn_kernel<<<4096, 256, 0, stream>>>(qkv, bias_f, mask, attn_out);

    // out = attn_out @ w_proj + b_proj
    gemm_bias_kernel<<<dim3(256 / 64, 4096 / 64), 256, 0, stream>>>(
        attn_out, w_proj, b_proj, out, 4096, 256, 256);
}

// Round 2
// 67.740 us; speedup vs baseline: 1.3687x; 1.3687x over previous
//
#include <hip/hip_runtime.h>
#include <math.h>

typedef __attribute__((ext_vector_type(8))) short bf16x8;   // 8 bf16 raw bits
typedef __attribute__((ext_vector_type(4))) float f32x4;

__device__ inline ushort f2bf(float f) {
    union { float f; uint u; } v; v.f = f;
    uint u = v.u;
    uint r = (u + 0x7fff + ((u >> 16) & 1)) >> 16;   // round-nearest-even
    return (ushort)r;
}

// ---------------------------------------------------------------------------
// Prep: xb = bf16(x); wqkvT = bf16(w_qkv^T); wprojT = bf16(w_proj^T)
// grid = 512 + 192 + 64 = 768 blocks of 256
// ---------------------------------------------------------------------------
__global__ __launch_bounds__(256) void prep_kernel(
    const float* __restrict__ x, const float* __restrict__ wqkv,
    const float* __restrict__ wproj,
    ushort* __restrict__ xb, ushort* __restrict__ wqkvT, ushort* __restrict__ wprojT)
{
    const int b = blockIdx.x, t = threadIdx.x;
    if (b < 512) {
        // x: 4096*256 f32 -> bf16, 8 per thread
        size_t i8 = (size_t)(b * 256 + t);
        const float4* src = (const float4*)x + i8 * 2;
        float4 v0 = src[0], v1 = src[1];
        bf16x8 o;
        o[0] = (short)f2bf(v0.x); o[1] = (short)f2bf(v0.y);
        o[2] = (short)f2bf(v0.z); o[3] = (short)f2bf(v0.w);
        o[4] = (short)f2bf(v1.x); o[5] = (short)f2bf(v1.y);
        o[6] = (short)f2bf(v1.z); o[7] = (short)f2bf(v1.w);
        *(bf16x8*)(xb + i8 * 8) = o;
    } else if (b < 704) {
        // w_qkv (256 x 768) -> wqkvT (768 x 256) bf16
        int q = (b - 512) * 256 + t;          // 0..49151
        int n4 = q % 192, k = q / 192;
        float4 v = *(const float4*)&wqkv[(size_t)k * 768 + n4 * 4];
        wqkvT[(size_t)(n4 * 4 + 0) * 256 + k] = f2bf(v.x);
        wqkvT[(size_t)(n4 * 4 + 1) * 256 + k] = f2bf(v.y);
        wqkvT[(size_t)(n4 * 4 + 2) * 256 + k] = f2bf(v.z);
        wqkvT[(size_t)(n4 * 4 + 3) * 256 + k] = f2bf(v.w);
    } else {
        // w_proj (256 x 256) -> wprojT (256 x 256) bf16
        int q = (b - 704) * 256 + t;          // 0..16383
        int n4 = q % 64, k = q / 64;
        float4 v = *(const float4*)&wproj[(size_t)k * 256 + n4 * 4];
        wprojT[(size_t)(n4 * 4 + 0) * 256 + k] = f2bf(v.x);
        wprojT[(size_t)(n4 * 4 + 1) * 256 + k] = f2bf(v.y);
        wprojT[(size_t)(n4 * 4 + 2) * 256 + k] = f2bf(v.z);
        wprojT[(size_t)(n4 * 4 + 3) * 256 + k] = f2bf(v.w);
    }
}

// ---------------------------------------------------------------------------
// MFMA bf16 GEMM: C(MxN,f32) = A(MxK,bf16 row-major) @ BT(NxK,bf16 row-major)^T + bias
// BK=32, 16x16x32 MFMA. LDS 16B-chunk swizzle: chunk g stored at g ^ ((row>>1)&3)
// -> 2-way worst-case bank conflict on both read and write (free).
// ---------------------------------------------------------------------------
template<int BM, int BN, int WGM, int WGN>
__global__ __launch_bounds__(WGM * WGN * 64) void mfma_gemm_bt(
    const ushort* __restrict__ A, const ushort* __restrict__ BT,
    const float* __restrict__ bias, float* __restrict__ C,
    int M, int N, int K)
{
    constexpr int BK = 32;
    constexpr int NT = WGM * WGN * 64;
    constexpr int WM = BM / (WGM * 16);   // 16x16 frags per wave, M dir
    constexpr int WN = BN / (WGN * 16);   // frags per wave, N dir

    __shared__ ushort As[BM * BK];
    __shared__ ushort Bs[BN * BK];

    const int tid = threadIdx.x;
    const int lane = tid & 63, wid = tid >> 6;
    const int wm = wid / WGN, wn = wid % WGN;
    const int row0 = blockIdx.x * BM, col0 = blockIdx.y * BN;
    const int frow = lane & 15, fg = lane >> 4;   // fragment row/col + k-group

    f32x4 acc[WM][WN] = {};

    for (int k0 = 0; k0 < K; k0 += BK) {
        // ---- stage (reg path, swizzled 16B chunks) ----
        #pragma unroll
        for (int ci = tid; ci < BM * 4; ci += NT) {
            int r = ci >> 2, g = ci & 3;
            bf16x8 v = *(const bf16x8*)&A[(size_t)(row0 + r) * K + k0 + g * 8];
            *(bf16x8*)&As[r * 32 + ((g ^ ((r >> 1) & 3)) << 3)] = v;
        }
        #pragma unroll
        for (int ci = tid; ci < BN * 4; ci += NT) {
            int r = ci >> 2, g = ci & 3;
            bf16x8 v = *(const bf16x8*)&BT[(size_t)(col0 + r) * K + k0 + g * 8];
            *(bf16x8*)&Bs[r * 32 + ((g ^ ((r >> 1) & 3)) << 3)] = v;
        }
        __syncthreads();

        // ---- fragments + MFMA ----
        bf16x8 af[WM], bf[WN];
        #pragma unroll
        for (int m = 0; m < WM; ++m) {
            int r = (wm * WM + m) * 16 + frow;
            af[m] = *(const bf16x8*)&As[r * 32 + ((fg ^ ((r >> 1) & 3)) << 3)];
        }
        #pragma unroll
        for (int n = 0; n < WN; ++n) {
            int r = (wn * WN + n) * 16 + frow;
            bf[n] = *(const bf16x8*)&Bs[r * 32 + ((fg ^ ((r >> 1) & 3)) << 3)];
        }
        #pragma unroll
        for (int m = 0; m < WM; ++m)
            #pragma unroll
            for (int n = 0; n < WN; ++n)
                acc[m][n] = __builtin_amdgcn_mfma_f32_16x16x32_bf16(
                    af[m], bf[n], acc[m][n], 0, 0, 0);
        __syncthreads();
    }

    // ---- epilogue: D[row=(lane>>4)*4+r][col=lane&15] (m89 layout) ----
    #pragma unroll
    for (int n = 0; n < WN; ++n) {
        int gcol = col0 + (wn * WN + n) * 16 + (lane & 15);
        float bv = bias[gcol];
        #pragma unroll
        for (int m = 0; m < WM; ++m) {
            int grow0 = row0 + (wm * WM + m) * 16 + (lane >> 4) * 4;
            #pragma unroll
            for (int r = 0; r < 4; ++r)
                C[(size_t)(grow0 + r) * N + gcol] = acc[m][n][r] + bv;
        }
    }
}

// ---------------------------------------------------------------------------
// Fused relational attention. One block per (bt, i). attn_out written as bf16.
// ---------------------------------------------------------------------------
__global__ __launch_bounds__(256) void relattn_kernel(
    const float* __restrict__ qkv, const float* __restrict__ bias,
    const int* __restrict__ mask, ushort* __restrict__ attn_out)
{
    __shared__ float bias_lds[8192];  // swizzled float4 layout: (j, c) at c^(j&7)
    __shared__ float p_lds[256];      // p_lds[h*32 + j]

    const int blk = blockIdx.x;       // bt*32 + i
    const int bt = blk >> 5;
    const int tid = threadIdx.x;

    // stage bias slab (32 KB), XOR-swizzled at float4 granularity
    const float* bsrc = bias + (size_t)blk * 8192;
    #pragma unroll
    for (int it = 0; it < 8; ++it) {
        int idx4 = it * 256 + tid;
        float4 v = *(const float4*)(bsrc + (size_t)idx4 * 4);
        int j = idx4 >> 6, c = idx4 & 63;
        int dst4 = (j << 6) | (c ^ (j & 7));
        *(float4*)&bias_lds[dst4 * 4] = v;
    }
    __syncthreads();

    // scores: thread = (h, j)
    const int j = tid & 31, h = tid >> 5;
    const float* qrow = qkv + (size_t)blk * 768 + h * 32;
    const float* krow = qkv + (size_t)(bt * 32 + j) * 768 + 256 + h * 32;
    float s = 0.f;
    #pragma unroll
    for (int d4 = 0; d4 < 8; ++d4) {
        float4 qv = *(const float4*)(qrow + d4 * 4);
        float4 kv = *(const float4*)(krow + d4 * 4);
        int c = (h * 8 + d4) ^ (j & 7);
        float4 bv = *(const float4*)&bias_lds[(j * 64 + c) * 4];
        s += qv.x * (kv.x + bv.x) + qv.y * (kv.y + bv.y)
           + qv.z * (kv.z + bv.z) + qv.w * (kv.w + bv.w);
    }
    s *= 0.17677669529663687f;  // 1/sqrt(32)

    const bool alive = (mask[bt * 32 + j] != 0);
    s = alive ? s : -__builtin_inff();

    float m = s;
    #pragma unroll
    for (int off = 16; off; off >>= 1) m = fmaxf(m, __shfl_xor(m, off));
    const bool dead = (m == -__builtin_inff());
    float p = alive ? __expf(s - m) : 0.f;
    float l = p;
    #pragma unroll
    for (int off = 16; off; off >>= 1) l += __shfl_xor(l, off);
    float pn = dead ? 0.f : p / l;
    p_lds[tid] = pn;
    __syncthreads();

    // PV: thread = (h2, d)
    const float* vcol = qkv + (size_t)bt * 32 * 768 + 512 + tid;
    const int hbase = tid & 0xE0;
    float o = 0.f;
    #pragma unroll
    for (int jj = 0; jj < 32; ++jj) {
        float pv = p_lds[hbase + jj];
        float vv = vcol[(size_t)jj * 768];
        int cblk = (tid >> 2) ^ (jj & 7);
        float bb = bias_lds[(jj * 64 + cblk) * 4 + (tid & 3)];
        o += pv * (vv + bb);
    }
    attn_out[(size_t)blk * 256 + tid] = f2bf(o);
}

extern "C" void kernel_launch(void* const* d_in, const int* in_sizes, int n_in,
                              void* d_out, int out_size, void* d_ws, size_t ws_size,
                              hipStream_t stream) {
    const float* x      = (const float*)d_in[0];   // (4096,256)
    const float* bias_f = (const float*)d_in[1];   // (4096,32,256)
    const int*   mask   = (const int*)d_in[2];     // (4096,)
    const float* w_qkv  = (const float*)d_in[3];   // (256,768)
    const float* b_qkv  = (const float*)d_in[4];   // (768,)
    const float* w_proj = (const float*)d_in[5];   // (256,256)
    const float* b_proj = (const float*)d_in[6];   // (256,)
    float* out = (float*)d_out;                    // (4096,256)

    // workspace layout (bytes):
    //   qkv f32      : 0            .. 12,582,912
    //   xb / attn_out: 12,582,912   .. 14,680,064   (xb dead after gemm1; reused)
    //   wqkvT bf16   : 14,680,064   .. 15,073,280
    //   wprojT bf16  : 15,073,280   .. 15,204,352
    char* ws = (char*)d_ws;
    float*  qkv      = (float*)ws;
    ushort* xb       = (ushort*)(ws + 12582912);
    ushort* attn_o   = xb;                          // reuse after gemm1
    ushort* wqkvT    = (ushort*)(ws + 14680064);
    ushort* wprojT   = (ushort*)(ws + 15073280);

    prep_kernel<<<768, 256, 0, stream>>>(x, w_qkv, w_proj, xb, wqkvT, wprojT);

    // qkv = x @ w_qkv + b_qkv   (M=4096, N=768, K=256)
    mfma_gemm_bt<128, 64, 2, 2><<<dim3(4096 / 128, 768 / 64), 256, 0, stream>>>(
        xb, wqkvT, b_qkv, qkv, 4096, 768, 256);

    relattn_kernel<<<4096, 256, 0, stream>>>(qkv, bias_f, mask, attn_o);

    // out = attn_out @ w_proj + b_proj   (M=4096, N=256, K=256)
    mfma_gemm_bt<64, 64, 2, 2><<<dim3(4096 / 64, 256 / 64), 256, 0, stream>>>(
        attn_o, wprojT, b_proj, out, 4096, 256, 256);
}

// Round 3
// 60.417 us; speedup vs baseline: 1.5346x; 1.1212x over previous
//
#include <hip/hip_runtime.h>
#include <math.h>

typedef __attribute__((ext_vector_type(8))) short bf16x8;
typedef __attribute__((ext_vector_type(4))) short bf16x4;
typedef __attribute__((ext_vector_type(4))) float f32x4;

__device__ inline ushort f2bf(float f) {
    union { float f; uint u; } v; v.f = f;
    uint u = v.u;
    return (ushort)((u + 0x7fff + ((u >> 16) & 1)) >> 16);   // RNE
}
__device__ inline float bf2f(ushort u) {
    union { uint u; float f; } v; v.u = ((uint)u) << 16; return v.f;
}

#ifndef __has_builtin
#define __has_builtin(x) 0
#endif
#if __has_builtin(__builtin_amdgcn_global_load_lds)
#define HAVE_GLL 1
typedef __attribute__((address_space(1))) const void global_void;
typedef __attribute__((address_space(3))) void lds_void;
__device__ inline void gl_lds16(const void* g, void* l) {
    __builtin_amdgcn_global_load_lds((global_void*)g, (lds_void*)l, 16, 0, 0);
}
#else
#define HAVE_GLL 0
#endif

// ---------------------------------------------------------------------------
// MFMA bf16 GEMM, converts inputs on the fly.
//   A: MODE0 = f32 row-major (lda=K), MODE1 = bf16 row-major (lda=K)
//   B: f32 row-major (K x N, ldb), transposed+converted into LDS
//   out: MODE0 = bf16 split into 3 buffers of 256 cols (q,k,v); MODE1 = f32
// LDS 16B-chunk XOR swizzle: chunk g of row r stored at g ^ ((r>>1)&3)  (2-way max)
// ---------------------------------------------------------------------------
template<int BM, int BN, int WGM, int WGN, int MODE>
__global__ __launch_bounds__(WGM * WGN * 64) void gemm_fused(
    const void* __restrict__ Ap, const float* __restrict__ Bw, int ldb,
    const float* __restrict__ bias,
    void* __restrict__ C0, void* __restrict__ C1, void* __restrict__ C2,
    int K, int N)
{
    constexpr int BK = 32;
    constexpr int NT = WGM * WGN * 64;
    constexpr int WM = BM / (WGM * 16);
    constexpr int WN = BN / (WGN * 16);

    __shared__ ushort As[BM * BK];
    __shared__ ushort Bs[BN * BK];

    const int tid = threadIdx.x;
    const int lane = tid & 63, wid = tid >> 6;
    const int wm = wid / WGN, wn = wid % WGN;
    const int row0 = blockIdx.y * BM, col0 = blockIdx.x * BN;
    const int frow = lane & 15, fg = lane >> 4;

    f32x4 acc[WM][WN] = {};

    for (int k0 = 0; k0 < K; k0 += BK) {
        if constexpr (MODE == 0) {
            #pragma unroll
            for (int ci = tid; ci < BM * 8; ci += NT) {
                int r = ci >> 3, kq = ci & 7, g = kq >> 1;
                float4 v = *(const float4*)((const float*)Ap + (size_t)(row0 + r) * K + k0 + kq * 4);
                bf16x4 o;
                o[0] = (short)f2bf(v.x); o[1] = (short)f2bf(v.y);
                o[2] = (short)f2bf(v.z); o[3] = (short)f2bf(v.w);
                *(bf16x4*)&As[r * 32 + ((g ^ ((r >> 1) & 3)) << 3) + (kq & 1) * 4] = o;
            }
        } else {
            #pragma unroll
            for (int ci = tid; ci < BM * 4; ci += NT) {
                int r = ci >> 2, g = ci & 3;
                bf16x8 v = *(const bf16x8*)((const ushort*)Ap + (size_t)(row0 + r) * K + k0 + g * 8);
                *(bf16x8*)&As[r * 32 + ((g ^ ((r >> 1) & 3)) << 3)] = v;
            }
        }
        // B: read f32 (k-row, n-cols) and transpose into Bs[n][k]
        #pragma unroll
        for (int ci = tid; ci < BN * 8; ci += NT) {
            int kk = ci & 31, n4 = ci >> 5;
            float4 v = *(const float4*)&Bw[(size_t)(k0 + kk) * ldb + col0 + n4 * 4];
            float vv[4] = {v.x, v.y, v.z, v.w};
            #pragma unroll
            for (int e = 0; e < 4; ++e) {
                int n = n4 * 4 + e;
                Bs[n * 32 + (((kk >> 3) ^ ((n >> 1) & 3)) << 3) + (kk & 7)] = f2bf(vv[e]);
            }
        }
        __syncthreads();

        bf16x8 af[WM], bfr[WN];
        #pragma unroll
        for (int m = 0; m < WM; ++m) {
            int r = (wm * WM + m) * 16 + frow;
            af[m] = *(const bf16x8*)&As[r * 32 + ((fg ^ ((r >> 1) & 3)) << 3)];
        }
        #pragma unroll
        for (int n = 0; n < WN; ++n) {
            int r = (wn * WN + n) * 16 + frow;
            bfr[n] = *(const bf16x8*)&Bs[r * 32 + ((fg ^ ((r >> 1) & 3)) << 3)];
        }
        #pragma unroll
        for (int m = 0; m < WM; ++m)
            #pragma unroll
            for (int n = 0; n < WN; ++n)
                acc[m][n] = __builtin_amdgcn_mfma_f32_16x16x32_bf16(
                    af[m], bfr[n], acc[m][n], 0, 0, 0);
        __syncthreads();
    }

    // epilogue: D[row=(lane>>4)*4+r][col=lane&15]
    #pragma unroll
    for (int n = 0; n < WN; ++n) {
        int gcol = col0 + (wn * WN + n) * 16 + frow;
        float bv = bias[gcol];
        if constexpr (MODE == 0) {
            int b = gcol >> 8, c = gcol & 255;
            ushort* dst = (b == 0) ? (ushort*)C0 : (b == 1) ? (ushort*)C1 : (ushort*)C2;
            #pragma unroll
            for (int m = 0; m < WM; ++m) {
                int grow0 = row0 + (wm * WM + m) * 16 + fg * 4;
                #pragma unroll
                for (int r = 0; r < 4; ++r)
                    dst[(size_t)(grow0 + r) * 256 + c] = f2bf(acc[m][n][r] + bv);
            }
        } else {
            float* dst = (float*)C0;
            #pragma unroll
            for (int m = 0; m < WM; ++m) {
                int grow0 = row0 + (wm * WM + m) * 16 + fg * 4;
                #pragma unroll
                for (int r = 0; r < 4; ++r)
                    dst[(size_t)(grow0 + r) * N + gcol] = acc[m][n][r] + bv;
            }
        }
    }
}

// ---------------------------------------------------------------------------
// Fused relational attention. One block per (bt, i). q/k/v bf16, bias f32.
// bias LDS layout: float4 chunk (j, c) stored at chunk index c ^ (j&7).
// ---------------------------------------------------------------------------
__global__ __launch_bounds__(256) void relattn_kernel(
    const ushort* __restrict__ qb, const ushort* __restrict__ kb,
    const ushort* __restrict__ vb, const float* __restrict__ bias,
    const int* __restrict__ mask, ushort* __restrict__ attn_out)
{
    __shared__ float bias_lds[8192];
    __shared__ float p_lds[256];

    const int blk = blockIdx.x;       // bt*32 + i
    const int bt = blk >> 5;
    const int tid = threadIdx.x;
    const int lane = tid & 63, wid = tid >> 6;
    const float* bsrc = bias + (size_t)blk * 8192;

#if HAVE_GLL
    // async global->LDS: linear LDS dest (wave-uniform base + lane*16),
    // swizzle realized by permuting the per-lane SOURCE chunk address.
    #pragma unroll
    for (int it = 0; it < 8; ++it) {
        int j = it * 4 + wid;
        const float* src = bsrc + (size_t)((j << 6) | (lane ^ (j & 7))) * 4;
        gl_lds16(src, &bias_lds[j * 256]);
    }
#else
    #pragma unroll
    for (int it = 0; it < 8; ++it) {
        int idx4 = it * 256 + tid;
        float4 v = *(const float4*)(bsrc + (size_t)idx4 * 4);
        int j = idx4 >> 6, c = idx4 & 63;
        *(float4*)&bias_lds[((j << 6) | (c ^ (j & 7))) * 4] = v;
    }
#endif
    __syncthreads();

    // scores: thread = (h, j)
    const int j = tid & 31, h = tid >> 5;
    const ushort* qrow = qb + (size_t)blk * 256 + h * 32;
    const ushort* krow = kb + (size_t)(bt * 32 + j) * 256 + h * 32;
    float s = 0.f;
    #pragma unroll
    for (int it = 0; it < 4; ++it) {
        bf16x8 q8 = *(const bf16x8*)(qrow + it * 8);
        bf16x8 k8 = *(const bf16x8*)(krow + it * 8);
        int c0 = h * 8 + it * 2;
        float4 b0 = *(const float4*)&bias_lds[((j << 6) | (c0 ^ (j & 7))) * 4];
        float4 b1 = *(const float4*)&bias_lds[((j << 6) | ((c0 + 1) ^ (j & 7))) * 4];
        s += bf2f((ushort)q8[0]) * (bf2f((ushort)k8[0]) + b0.x)
           + bf2f((ushort)q8[1]) * (bf2f((ushort)k8[1]) + b0.y)
           + bf2f((ushort)q8[2]) * (bf2f((ushort)k8[2]) + b0.z)
           + bf2f((ushort)q8[3]) * (bf2f((ushort)k8[3]) + b0.w)
           + bf2f((ushort)q8[4]) * (bf2f((ushort)k8[4]) + b1.x)
           + bf2f((ushort)q8[5]) * (bf2f((ushort)k8[5]) + b1.y)
           + bf2f((ushort)q8[6]) * (bf2f((ushort)k8[6]) + b1.z)
           + bf2f((ushort)q8[7]) * (bf2f((ushort)k8[7]) + b1.w);
    }
    s *= 0.17677669529663687f;  // 1/sqrt(32)

    const bool alive = (mask[bt * 32 + j] != 0);
    s = alive ? s : -__builtin_inff();

    float m = s;
    #pragma unroll
    for (int off = 16; off; off >>= 1) m = fmaxf(m, __shfl_xor(m, off));
    const bool dead = (m == -__builtin_inff());
    float p = alive ? __expf(s - m) : 0.f;
    float l = p;
    #pragma unroll
    for (int off = 16; off; off >>= 1) l += __shfl_xor(l, off);
    p_lds[tid] = dead ? 0.f : p / l;
    __syncthreads();

    // PV: thread = (h2, d)
    const ushort* vcol = vb + (size_t)bt * 32 * 256 + tid;
    const int hbase = tid & 0xE0;
    float o = 0.f;
    #pragma unroll
    for (int jj = 0; jj < 32; ++jj) {
        float pv = p_lds[hbase + jj];
        float vv = bf2f(vcol[(size_t)jj * 256]);
        int cblk = (tid >> 2) ^ (jj & 7);
        float bb = bias_lds[(jj * 64 + cblk) * 4 + (tid & 3)];
        o += pv * (vv + bb);
    }
    attn_out[(size_t)blk * 256 + tid] = f2bf(o);
}

extern "C" void kernel_launch(void* const* d_in, const int* in_sizes, int n_in,
                              void* d_out, int out_size, void* d_ws, size_t ws_size,
                              hipStream_t stream) {
    const float* x      = (const float*)d_in[0];   // (4096,256)
    const float* bias_f = (const float*)d_in[1];   // (4096,32,256)
    const int*   mask   = (const int*)d_in[2];     // (4096,)
    const float* w_qkv  = (const float*)d_in[3];   // (256,768)
    const float* b_qkv  = (const float*)d_in[4];   // (768,)
    const float* w_proj = (const float*)d_in[5];   // (256,256)
    const float* b_proj = (const float*)d_in[6];   // (256,)
    float* out = (float*)d_out;                    // (4096,256)

    // workspace: q,k,v,attn_out each 4096*256 bf16 (2 MB) = 8.4 MB total
    ushort* qb = (ushort*)d_ws;
    ushort* kb = qb + (size_t)4096 * 256;
    ushort* vb = kb + (size_t)4096 * 256;
    ushort* ao = vb + (size_t)4096 * 256;

    // qkv = x @ w_qkv + b_qkv  ->  bf16 q/k/v   (M=4096, N=768, K=256)
    gemm_fused<64, 64, 2, 2, 0><<<dim3(12, 64), 256, 0, stream>>>(
        x, w_qkv, 768, b_qkv, qb, kb, vb, 256, 768);

    relattn_kernel<<<4096, 256, 0, stream>>>(qb, kb, vb, bias_f, mask, ao);

    // out = attn_out @ w_proj + b_proj   (M=4096, N=256, K=256)
    gemm_fused<32, 64, 1, 4, 1><<<dim3(4, 128), 256, 0, stream>>>(
        ao, w_proj, 256, b_proj, out, nullptr, nullptr, 256, 256);
}